// Round 2
// baseline (610.859 us; speedup 1.0000x reference)
//
#include <hip/hip_runtime.h>

// Problem constants (T=64, B=32, I=128, H=256, alpha=0.2)
#define TT 64
#define BB 32
#define II 128
#define HH 256
#define MM (TT*BB)   // 2048

typedef __bf16  bf16x8  __attribute__((ext_vector_type(8)));
typedef float   f32x16  __attribute__((ext_vector_type(16)));
typedef _Float16 half2v __attribute__((ext_vector_type(2)));

__device__ __forceinline__ float bf2f(unsigned short u) {
    union { unsigned int i; float f; } v; v.i = ((unsigned int)u) << 16; return v.f;
}
__device__ __forceinline__ unsigned short f2bf(float f) {
    union { float f; unsigned int i; } v; v.f = f;
    unsigned int r = v.i + 0x7fffu + ((v.i >> 16) & 1u);
    return (unsigned short)(r >> 16);
}

// Dual-dtype loaders: external tensors may be fp32 or bf16; runtime flag decides.
struct F8 { float v[8]; };
__device__ __forceinline__ F8 load8(const void* base, int idx, int isf32) {
    F8 r;
    if (isf32) {
        const float4* p = (const float4*)((const float*)base + idx);
        float4 a = p[0], b = p[1];
        r.v[0]=a.x; r.v[1]=a.y; r.v[2]=a.z; r.v[3]=a.w;
        r.v[4]=b.x; r.v[5]=b.y; r.v[6]=b.z; r.v[7]=b.w;
    } else {
        uint4 u = *(const uint4*)((const unsigned short*)base + idx);
        const unsigned short* p = (const unsigned short*)&u;
#pragma unroll
        for (int j = 0; j < 8; ++j) r.v[j] = bf2f(p[j]);
    }
    return r;
}
__device__ __forceinline__ float load1(const void* base, int idx, int isf32) {
    return isf32 ? ((const float*)base)[idx]
                 : bf2f(((const unsigned short*)base)[idx]);
}

// ---------------------------------------------------------------------------
// K0: dtype sniffer. bf16(N(0,1)) ushorts have exponent field <= ~0x82.
// fp32 read as ushorts: even indices are raw mantissa words -> ~25% have
// exponent >= 0xC0. Count over 8192 ushorts of x; decisive either way.
// ---------------------------------------------------------------------------
__global__ __launch_bounds__(256) void k0_sniff(
    const unsigned short* __restrict__ x, int* __restrict__ flag)
{
    __shared__ int cnt;
    if (threadIdx.x == 0) cnt = 0;
    __syncthreads();
    int c = 0;
    for (int i = threadIdx.x; i < 8192; i += 256) {
        unsigned int e = (x[i] >> 7) & 0xFFu;
        if (e >= 0xC0u) ++c;
    }
    atomicAdd(&cnt, c);
    __syncthreads();
    if (threadIdx.x == 0) flag[0] = (cnt > 16) ? 1 : 0;
}

// ---------------------------------------------------------------------------
// K1: ip[m,h] = x[m,:]@w_i2h[h,:] + b_i2h[h]  (bf16, internal ws)
//     cin[m,h] = x[m,:]@w_i2c[h,:] + b_i2c[h] (fp32, internal ws)
// ---------------------------------------------------------------------------
__global__ __launch_bounds__(256) void k1_proj(
    const void* __restrict__ x,
    const void* __restrict__ w_i2h,
    const void* __restrict__ b_i2h,
    const void* __restrict__ w_i2c,
    const void* __restrict__ b_i2c,
    const int* __restrict__ flagp,
    unsigned short* __restrict__ ip,
    float* __restrict__ cin)
{
    const int isf32 = *flagp;
    const int m = blockIdx.x;
    const int tid = threadIdx.x;
    __shared__ __align__(16) float xs[II];
    if (tid < II) xs[tid] = load1(x, m*II + tid, isf32);
    __syncthreads();
    const int h = tid;
    float a1 = load1(b_i2h, h, isf32);
    float a2 = load1(b_i2c, h, isf32);
#pragma unroll
    for (int c = 0; c < II/8; ++c) {
        F8 f1 = load8(w_i2h, h*II + c*8, isf32);
        F8 f2 = load8(w_i2c, h*II + c*8, isf32);
#pragma unroll
        for (int j = 0; j < 8; ++j) {
            float xv = xs[c*8 + j];
            a1 = fmaf(f1.v[j], xv, a1);
            a2 = fmaf(f2.v[j], xv, a2);
        }
    }
    ip[m*HH + h]  = f2bf(a1);
    cin[m*HH + h] = a2;
}

// ---------------------------------------------------------------------------
// K2: per-sample context chains (32 blocks = b; 256 threads = h).
// w_c2c row resident in VGPRs as f16x2 + fdot2. Records ctx entering the
// LAST sub-step (feeds `transformed`); writes final context into d_out's
// third chunk (element offset MM*HH + BB*HH), honoring dtype flag.
// ---------------------------------------------------------------------------
__global__ __launch_bounds__(256) void k2_ctx(
    const void* __restrict__ w_c2c,
    const void* __restrict__ b_c2c,
    const float* __restrict__ cin,
    const int* __restrict__ ns_ptr,
    const int* __restrict__ flagp,
    unsigned short* __restrict__ ctx_hist,
    void* __restrict__ out_base)
{
    const int isf32 = *flagp;
    const int b = blockIdx.x;
    const int h = threadIdx.x;
    const int ns = max(1, *ns_ptr);

    __shared__ __align__(16) _Float16 cs[HH];

    half2v w[HH/2];
#pragma unroll
    for (int c8 = 0; c8 < HH/8; ++c8) {
        F8 f = load8(w_c2c, h*HH + c8*8, isf32);
#pragma unroll
        for (int j = 0; j < 4; ++j) {
            half2v hv;
            hv.x = (_Float16)f.v[2*j];
            hv.y = (_Float16)f.v[2*j+1];
            w[c8*4 + j] = hv;
        }
    }
    const float bcc = load1(b_c2c, h, isf32);
    float ctxv = 0.0f;
    cs[h] = (_Float16)0.0f;
    __syncthreads();

    for (int t = 0; t < TT; ++t) {
        const float cinv = cin[(t*BB + b)*HH + h];
        for (int s = 0; s < ns; ++s) {
            if (s == ns-1) ctx_hist[(t*BB + b)*HH + h] = f2bf(ctxv);
            float acc = bcc + cinv;
            const float4* cp4 = (const float4*)cs;   // 16B = 4 half2
#pragma unroll
            for (int r4 = 0; r4 < HH/8; ++r4) {
                float4 blob = cp4[r4];
                const half2v* c2 = (const half2v*)&blob;
#pragma unroll
                for (int j = 0; j < 4; ++j) {
#if __has_builtin(__builtin_amdgcn_fdot2)
                    acc = __builtin_amdgcn_fdot2(w[r4*4 + j], c2[j], acc, false);
#else
                    acc += (float)w[r4*4 + j].x * (float)c2[j].x
                         + (float)w[r4*4 + j].y * (float)c2[j].y;
#endif
                }
            }
            float cnew = fmaxf(acc, 0.0f);
            ctxv = 0.8f*ctxv + 0.2f*cnew;
            __syncthreads();           // everyone done reading cs
            cs[h] = (_Float16)ctxv;
            __syncthreads();           // writes visible
        }
    }
    const int cofs = MM*HH + BB*HH + b*HH + h;
    if (isf32) ((float*)out_base)[cofs] = ctxv;
    else       ((unsigned short*)out_base)[cofs] = f2bf(ctxv);
}

// ---------------------------------------------------------------------------
// K3: for each (m-block of 128, i): TM[m,j] = ctx[m,:]@Wc[i*256+j,:]^T (MFMA),
// then out[m,i] = sum_j (TM[m,j] + bc[i*256+j]) * ip[m,j].
// 32x32x16 bf16 MFMA, wave-tile 64m x 128j, K=256 in 4 chunks of 64.
// ---------------------------------------------------------------------------
#define KC   64
#define AROW 72
#define BROW 72
#define A_BYTES (128*AROW*2)          // 18432
#define B_BYTES (256*BROW*2)          // 36864
#define TMROW 258
#define LDS_TOTAL (A_BYTES + B_BYTES + 32*9*4)

__global__ __launch_bounds__(256) void k3_main(
    const unsigned short* __restrict__ ctx_hist,  // [2048,256] bf16 (internal)
    const void* __restrict__ wc,                  // [65536,256] external
    const void* __restrict__ bc,                  // [65536]     external
    const unsigned short* __restrict__ ip,        // [2048,256] bf16 (internal)
    const int* __restrict__ flagp,
    void* __restrict__ out)
{
    const int isf32 = *flagp;
    __shared__ __align__(16) unsigned char lds[LDS_TOTAL];
    unsigned short* As = (unsigned short*)lds;              // [128][72]
    unsigned short* Bs = (unsigned short*)(lds + A_BYTES);  // [256][72]
    float* TM   = (float*)lds;                              // [32][258] overlay
    float* part = (float*)(lds + A_BYTES + B_BYTES);        // [32][9]

    const int tid  = threadIdx.x;
    const int lane = tid & 63;
    const int wave = tid >> 6;
    const int mb = blockIdx.x;          // 0..15
    const int i  = blockIdx.y;          // 0..255
    const int m0 = mb * 128;
    const int mhalf = wave & 1;
    const int jhalf = wave >> 1;
    const int l31 = lane & 31;
    const int khi = (lane >> 5) * 8;

    f32x16 acc[2][4];
#pragma unroll
    for (int a = 0; a < 2; ++a)
#pragma unroll
        for (int n = 0; n < 4; ++n)
#pragma unroll
            for (int r = 0; r < 16; ++r) acc[a][n][r] = 0.0f;

#pragma unroll
    for (int kc = 0; kc < 4; ++kc) {
        const int k0 = kc * KC;
        // stage A: 128 rows x 64 k (internal bf16, plain copy)
#pragma unroll
        for (int p = 0; p < 4; ++p) {
            int unit = tid + p*256;
            int row = unit >> 3, uc = unit & 7;
            uint4 v = *(const uint4*)(ctx_hist + (m0+row)*HH + k0 + uc*8);
            *(uint4*)(As + row*AROW + uc*8) = v;
        }
        // stage B: 256 rows x 64 k (external, dual dtype -> bf16 in LDS)
#pragma unroll
        for (int p = 0; p < 8; ++p) {
            int unit = tid + p*256;
            int row = unit >> 3, uc = unit & 7;
            F8 f = load8(wc, (i*HH + row)*HH + k0 + uc*8, isf32);
            unsigned short tmp[8];
#pragma unroll
            for (int j = 0; j < 8; ++j) tmp[j] = f2bf(f.v[j]);
            *(uint4*)(Bs + row*BROW + uc*8) = *(const uint4*)tmp;
        }
        __syncthreads();
#pragma unroll
        for (int ks = 0; ks < 4; ++ks) {
            const int kk = ks*16 + khi;
            bf16x8 a0 = *(const bf16x8*)(As + (mhalf*64 +      l31)*AROW + kk);
            bf16x8 a1 = *(const bf16x8*)(As + (mhalf*64 + 32 + l31)*AROW + kk);
            bf16x8 b0 = *(const bf16x8*)(Bs + (jhalf*128 +      l31)*BROW + kk);
            bf16x8 b1 = *(const bf16x8*)(Bs + (jhalf*128 + 32 + l31)*BROW + kk);
            bf16x8 b2 = *(const bf16x8*)(Bs + (jhalf*128 + 64 + l31)*BROW + kk);
            bf16x8 b3 = *(const bf16x8*)(Bs + (jhalf*128 + 96 + l31)*BROW + kk);
            acc[0][0] = __builtin_amdgcn_mfma_f32_32x32x16_bf16(a0, b0, acc[0][0], 0, 0, 0);
            acc[0][1] = __builtin_amdgcn_mfma_f32_32x32x16_bf16(a0, b1, acc[0][1], 0, 0, 0);
            acc[0][2] = __builtin_amdgcn_mfma_f32_32x32x16_bf16(a0, b2, acc[0][2], 0, 0, 0);
            acc[0][3] = __builtin_amdgcn_mfma_f32_32x32x16_bf16(a0, b3, acc[0][3], 0, 0, 0);
            acc[1][0] = __builtin_amdgcn_mfma_f32_32x32x16_bf16(a1, b0, acc[1][0], 0, 0, 0);
            acc[1][1] = __builtin_amdgcn_mfma_f32_32x32x16_bf16(a1, b1, acc[1][1], 0, 0, 0);
            acc[1][2] = __builtin_amdgcn_mfma_f32_32x32x16_bf16(a1, b2, acc[1][2], 0, 0, 0);
            acc[1][3] = __builtin_amdgcn_mfma_f32_32x32x16_bf16(a1, b3, acc[1][3], 0, 0, 0);
        }
        __syncthreads();
    }

    // Epilogue: 4 m-quarters of 32 rows. Quarter q -> (mhalf=q>>1, msub=q&1).
    const int rbase = 4*(lane >> 5);
#pragma unroll
    for (int q = 0; q < 4; ++q) {
        if ((wave & 1) == (q >> 1)) {
            const int msub = q & 1;
#pragma unroll
            for (int n = 0; n < 4; ++n) {
                const int c = jhalf*128 + n*32 + l31;
#pragma unroll
                for (int r = 0; r < 16; ++r) {
                    const int row = (r & 3) + 8*(r >> 2) + rbase;
                    TM[row*TMROW + c] = acc[msub][n][r];
                }
            }
        }
        __syncthreads();
        {
            const int ml  = tid & 31;
            const int cs8 = tid >> 5;          // 0..7, 32 cols each
            const int mg  = m0 + q*32 + ml;
            const float* tmr = TM + ml*TMROW + cs8*32;
            const unsigned short* ipr = ip + mg*HH + cs8*32;
            float s = 0.0f;
#pragma unroll
            for (int c8 = 0; c8 < 4; ++c8) {
                uint4 uip = *(const uint4*)(ipr + c8*8);
                const unsigned short* pi = (const unsigned short*)&uip;
                F8 fb = load8(bc, i*HH + cs8*32 + c8*8, isf32);
#pragma unroll
                for (int j = 0; j < 8; ++j)
                    s = fmaf(tmr[c8*8 + j] + fb.v[j], bf2f(pi[j]), s);
            }
            part[ml*9 + cs8] = s;
        }
        __syncthreads();
        if (tid < 32) {
            float s = 0.0f;
#pragma unroll
            for (int w2 = 0; w2 < 8; ++w2) s += part[tid*9 + w2];
            const int mg = m0 + q*32 + tid;
            if (isf32) {
                float* o = (float*)out;
                o[mg*HH + i] = s;
                if (mg >= MM - BB) o[MM*HH + (mg - (MM-BB))*HH + i] = s;
            } else {
                unsigned short* o = (unsigned short*)out;
                const unsigned short v = f2bf(s);
                o[mg*HH + i] = v;
                if (mg >= MM - BB) o[MM*HH + (mg - (MM-BB))*HH + i] = v;
            }
        }
        __syncthreads();
    }
}

// ---------------------------------------------------------------------------
extern "C" void kernel_launch(void* const* d_in, const int* in_sizes, int n_in,
                              void* d_out, int out_size, void* d_ws, size_t ws_size,
                              hipStream_t stream) {
    const void* x     = d_in[0];
    const void* w_i2h = d_in[1];
    const void* b_i2h = d_in[2];
    // d_in[3]=w_h2h, d_in[4]=b_h2h: dead code (reference overwrites hidden=transformed)
    const void* w_i2c = d_in[5];
    const void* b_i2c = d_in[6];
    const void* w_c2c = d_in[7];
    const void* b_c2c = d_in[8];
    const void* w_c2t = d_in[9];
    const void* b_c2t = d_in[10];
    const int* ns     = (const int*)d_in[11];

    // ws layout: ip bf16 [2048,256] | ctx_hist bf16 | cin f32 | flag int
    unsigned short* ip  = (unsigned short*)d_ws;
    unsigned short* ch  = (unsigned short*)((char*)d_ws + (size_t)MM*HH*2);
    float* cin          = (float*)((char*)d_ws + (size_t)MM*HH*4);
    int* flag           = (int*)((char*)d_ws + (size_t)MM*HH*8);

    k0_sniff<<<1, 256, 0, stream>>>((const unsigned short*)x, flag);
    k1_proj<<<MM, 256, 0, stream>>>(x, w_i2h, b_i2h, w_i2c, b_i2c, flag, ip, cin);
    k2_ctx<<<BB, 256, 0, stream>>>(w_c2c, b_c2c, cin, ns, flag, ch, d_out);
    k3_main<<<dim3(16, 256), 256, 0, stream>>>(ch, w_c2t, b_c2t, ip, flag, d_out);
}

// Round 3
// 501.054 us; speedup vs baseline: 1.2191x; 1.2191x over previous
//
#include <hip/hip_runtime.h>

// Problem constants (T=64, B=32, I=128, H=256, alpha=0.2)
#define TT 64
#define BB 32
#define II 128
#define HH 256
#define MM (TT*BB)   // 2048

typedef __bf16  bf16x8  __attribute__((ext_vector_type(8)));
typedef float   f32x16  __attribute__((ext_vector_type(16)));
typedef _Float16 half2v __attribute__((ext_vector_type(2)));

__device__ __forceinline__ float bf2f(unsigned short u) {
    union { unsigned int i; float f; } v; v.i = ((unsigned int)u) << 16; return v.f;
}
__device__ __forceinline__ unsigned short f2bf(float f) {
    union { float f; unsigned int i; } v; v.f = f;
    unsigned int r = v.i + 0x7fffu + ((v.i >> 16) & 1u);
    return (unsigned short)(r >> 16);
}

// Dual-dtype loaders: external tensors may be fp32 or bf16; runtime flag decides.
struct F8 { float v[8]; };
__device__ __forceinline__ F8 load8(const void* base, int idx, int isf32) {
    F8 r;
    if (isf32) {
        const float4* p = (const float4*)((const float*)base + idx);
        float4 a = p[0], b = p[1];
        r.v[0]=a.x; r.v[1]=a.y; r.v[2]=a.z; r.v[3]=a.w;
        r.v[4]=b.x; r.v[5]=b.y; r.v[6]=b.z; r.v[7]=b.w;
    } else {
        uint4 u = *(const uint4*)((const unsigned short*)base + idx);
        const unsigned short* p = (const unsigned short*)&u;
#pragma unroll
        for (int j = 0; j < 8; ++j) r.v[j] = bf2f(p[j]);
    }
    return r;
}
__device__ __forceinline__ float load1(const void* base, int idx, int isf32) {
    return isf32 ? ((const float*)base)[idx]
                 : bf2f(((const unsigned short*)base)[idx]);
}

__device__ __forceinline__ float fdot2f(half2v a, half2v b, float c) {
#if __has_builtin(__builtin_amdgcn_fdot2)
    return __builtin_amdgcn_fdot2(a, b, c, false);
#else
    return c + (float)a.x*(float)b.x + (float)a.y*(float)b.y;
#endif
}

// ---------------------------------------------------------------------------
// K0: dtype sniffer (fp32 read as ushorts -> ~25% have exponent >= 0xC0).
// ---------------------------------------------------------------------------
__global__ __launch_bounds__(256) void k0_sniff(
    const unsigned short* __restrict__ x, int* __restrict__ flag)
{
    __shared__ int cnt;
    if (threadIdx.x == 0) cnt = 0;
    __syncthreads();
    int c = 0;
    for (int i = threadIdx.x; i < 8192; i += 256) {
        unsigned int e = (x[i] >> 7) & 0xFFu;
        if (e >= 0xC0u) ++c;
    }
    atomicAdd(&cnt, c);
    __syncthreads();
    if (threadIdx.x == 0) flag[0] = (cnt > 16) ? 1 : 0;
}

// ---------------------------------------------------------------------------
// K1 v2: weights resident in VGPRs (f16x2), 32 m per block, grid 64.
// Weight global traffic: 64 x 262KB = 16.8 MB (was 537 MB).
// ip[m,h] bf16, cin[m,h] fp32.
// ---------------------------------------------------------------------------
__global__ __launch_bounds__(256) void k1_proj(
    const void* __restrict__ x,
    const void* __restrict__ w_i2h,
    const void* __restrict__ b_i2h,
    const void* __restrict__ w_i2c,
    const void* __restrict__ b_i2c,
    const int* __restrict__ flagp,
    unsigned short* __restrict__ ip,
    float* __restrict__ cin)
{
    const int isf32 = *flagp;
    const int tid = threadIdx.x;
    const int h = tid;
    const int mbase = blockIdx.x * 32;
    __shared__ __align__(16) _Float16 xs[32][II];   // 8 KB

    half2v w1[II/2], w2[II/2];
#pragma unroll
    for (int c8 = 0; c8 < II/8; ++c8) {
        F8 f1 = load8(w_i2h, h*II + c8*8, isf32);
        F8 f2 = load8(w_i2c, h*II + c8*8, isf32);
#pragma unroll
        for (int j = 0; j < 4; ++j) {
            half2v a; a.x = (_Float16)f1.v[2*j]; a.y = (_Float16)f1.v[2*j+1];
            half2v b; b.x = (_Float16)f2.v[2*j]; b.y = (_Float16)f2.v[2*j+1];
            w1[c8*4 + j] = a;
            w2[c8*4 + j] = b;
        }
    }
    const float bb1 = load1(b_i2h, h, isf32);
    const float bb2 = load1(b_i2c, h, isf32);

    for (int u = tid; u < 32*II; u += 256)
        xs[u >> 7][u & (II-1)] = (_Float16)load1(x, (mbase + (u >> 7))*II + (u & (II-1)), isf32);
    __syncthreads();

    for (int mm = 0; mm < 32; ++mm) {
        const half2v* xv = (const half2v*)xs[mm];
        float a0=0,a1=0,a2=0,a3=0, c0=0,c1=0,c2=0,c3=0;
#pragma unroll
        for (int r = 0; r < II/2; r += 4) {
            half2v x0 = xv[r], x1 = xv[r+1], x2 = xv[r+2], x3 = xv[r+3];
            a0 = fdot2f(w1[r],   x0, a0);
            a1 = fdot2f(w1[r+1], x1, a1);
            a2 = fdot2f(w1[r+2], x2, a2);
            a3 = fdot2f(w1[r+3], x3, a3);
            c0 = fdot2f(w2[r],   x0, c0);
            c1 = fdot2f(w2[r+1], x1, c1);
            c2 = fdot2f(w2[r+2], x2, c2);
            c3 = fdot2f(w2[r+3], x3, c3);
        }
        ip[(mbase+mm)*HH + h]  = f2bf(((a0+a1)+(a2+a3)) + bb1);
        cin[(mbase+mm)*HH + h] = ((c0+c1)+(c2+c3)) + bb2;
    }
}

// ---------------------------------------------------------------------------
// K2 v2: per-sample context chains. Double-buffered ctx in LDS (1 barrier per
// substep), 4-way accumulator ILP on the 256-wide dot.
// ---------------------------------------------------------------------------
__global__ __launch_bounds__(256) void k2_ctx(
    const void* __restrict__ w_c2c,
    const void* __restrict__ b_c2c,
    const float* __restrict__ cin,
    const int* __restrict__ ns_ptr,
    const int* __restrict__ flagp,
    unsigned short* __restrict__ ctx_hist,
    void* __restrict__ out_base)
{
    const int isf32 = *flagp;
    const int b = blockIdx.x;
    const int h = threadIdx.x;
    const int ns = max(1, *ns_ptr);

    __shared__ __align__(16) _Float16 cs[2][HH];

    half2v w[HH/2];
#pragma unroll
    for (int c8 = 0; c8 < HH/8; ++c8) {
        F8 f = load8(w_c2c, h*HH + c8*8, isf32);
#pragma unroll
        for (int j = 0; j < 4; ++j) {
            half2v hv;
            hv.x = (_Float16)f.v[2*j];
            hv.y = (_Float16)f.v[2*j+1];
            w[c8*4 + j] = hv;
        }
    }
    const float bcc = load1(b_c2c, h, isf32);
    float ctxv = 0.0f;
    cs[0][h] = (_Float16)0.0f;
    __syncthreads();
    int cur = 0;

    for (int t = 0; t < TT; ++t) {
        const float cinv = cin[(t*BB + b)*HH + h];
        for (int s = 0; s < ns; ++s) {
            if (s == ns-1) ctx_hist[(t*BB + b)*HH + h] = f2bf(ctxv);
            float p0=0,p1=0,p2=0,p3=0;
            const float4* cp4 = (const float4*)cs[cur];   // 16B = 4 half2
#pragma unroll
            for (int r4 = 0; r4 < HH/8; ++r4) {
                float4 blob = cp4[r4];
                const half2v* c2 = (const half2v*)&blob;
                p0 = fdot2f(w[r4*4+0], c2[0], p0);
                p1 = fdot2f(w[r4*4+1], c2[1], p1);
                p2 = fdot2f(w[r4*4+2], c2[2], p2);
                p3 = fdot2f(w[r4*4+3], c2[3], p3);
            }
            float cnew = fmaxf(((p0+p1)+(p2+p3)) + bcc + cinv, 0.0f);
            ctxv = 0.8f*ctxv + 0.2f*cnew;
            cs[cur^1][h] = (_Float16)ctxv;
            cur ^= 1;
            __syncthreads();
        }
    }
    const int cofs = MM*HH + BB*HH + b*HH + h;
    if (isf32) ((float*)out_base)[cofs] = ctxv;
    else       ((unsigned short*)out_base)[cofs] = f2bf(ctxv);
}

// ---------------------------------------------------------------------------
// K3 v2: grid (2 m-halves, 256 i) = 512 blocks, 2/CU, all resident.
// Each block loops 8 m-chunks x 4 k-chunks; the per-i B tile is re-read by
// the SAME CU -> XCD-L2 resident. Wave tile 64m x 128j, 32x32x16 bf16 MFMA.
// ---------------------------------------------------------------------------
#define KC   64
#define AROW 72
#define BROW 72
#define A_BYTES (128*AROW*2)          // 18432
#define B_BYTES (256*BROW*2)          // 36864
#define TMROW 258
#define LDS_TOTAL (A_BYTES + B_BYTES + 32*9*4)   // 56448

__global__ __launch_bounds__(256, 2) void k3_main(
    const unsigned short* __restrict__ ctx_hist,  // [2048,256] bf16 (internal)
    const void* __restrict__ wc,                  // [65536,256] external
    const void* __restrict__ bc,                  // [65536]     external
    const unsigned short* __restrict__ ip,        // [2048,256] bf16 (internal)
    const int* __restrict__ flagp,
    void* __restrict__ out)
{
    const int isf32 = *flagp;
    __shared__ __align__(16) unsigned char lds[LDS_TOTAL];
    unsigned short* As = (unsigned short*)lds;              // [128][72]
    unsigned short* Bs = (unsigned short*)(lds + A_BYTES);  // [256][72]
    float* TM   = (float*)lds;                              // [32][258] overlay
    float* part = (float*)(lds + A_BYTES + B_BYTES);        // [32][9]

    const int tid  = threadIdx.x;
    const int lane = tid & 63;
    const int wave = tid >> 6;
    const int mhB = blockIdx.x;         // 0..1
    const int i   = blockIdx.y;         // 0..255
    const int mhalf = wave & 1;
    const int jhalf = wave >> 1;
    const int l31 = lane & 31;
    const int khi = (lane >> 5) * 8;
    const int rbase = 4*(lane >> 5);

    for (int mc = 0; mc < 8; ++mc) {
        const int m0 = mhB*1024 + mc*128;

        f32x16 acc[2][4];
#pragma unroll
        for (int a = 0; a < 2; ++a)
#pragma unroll
            for (int n = 0; n < 4; ++n)
#pragma unroll
                for (int r = 0; r < 16; ++r) acc[a][n][r] = 0.0f;

#pragma unroll
        for (int kc = 0; kc < 4; ++kc) {
            const int k0 = kc * KC;
            // stage B: 256 rows x 64 k (L2-hot after first mc)
#pragma unroll
            for (int p = 0; p < 8; ++p) {
                int unit = tid + p*256;
                int row = unit >> 3, uc = unit & 7;
                F8 f = load8(wc, (i*HH + row)*HH + k0 + uc*8, isf32);
                unsigned short tmp[8];
#pragma unroll
                for (int j = 0; j < 8; ++j) tmp[j] = f2bf(f.v[j]);
                *(uint4*)(Bs + row*BROW + uc*8) = *(const uint4*)tmp;
            }
            // stage A: 128 rows x 64 k (internal bf16, plain copy)
#pragma unroll
            for (int p = 0; p < 4; ++p) {
                int unit = tid + p*256;
                int row = unit >> 3, uc = unit & 7;
                uint4 v = *(const uint4*)(ctx_hist + (m0+row)*HH + k0 + uc*8);
                *(uint4*)(As + row*AROW + uc*8) = v;
            }
            __syncthreads();
#pragma unroll
            for (int ks = 0; ks < 4; ++ks) {
                const int kk = ks*16 + khi;
                bf16x8 a0 = *(const bf16x8*)(As + (mhalf*64 +      l31)*AROW + kk);
                bf16x8 a1 = *(const bf16x8*)(As + (mhalf*64 + 32 + l31)*AROW + kk);
                bf16x8 b0 = *(const bf16x8*)(Bs + (jhalf*128 +      l31)*BROW + kk);
                bf16x8 b1 = *(const bf16x8*)(Bs + (jhalf*128 + 32 + l31)*BROW + kk);
                bf16x8 b2 = *(const bf16x8*)(Bs + (jhalf*128 + 64 + l31)*BROW + kk);
                bf16x8 b3 = *(const bf16x8*)(Bs + (jhalf*128 + 96 + l31)*BROW + kk);
                acc[0][0] = __builtin_amdgcn_mfma_f32_32x32x16_bf16(a0, b0, acc[0][0], 0, 0, 0);
                acc[0][1] = __builtin_amdgcn_mfma_f32_32x32x16_bf16(a0, b1, acc[0][1], 0, 0, 0);
                acc[0][2] = __builtin_amdgcn_mfma_f32_32x32x16_bf16(a0, b2, acc[0][2], 0, 0, 0);
                acc[0][3] = __builtin_amdgcn_mfma_f32_32x32x16_bf16(a0, b3, acc[0][3], 0, 0, 0);
                acc[1][0] = __builtin_amdgcn_mfma_f32_32x32x16_bf16(a1, b0, acc[1][0], 0, 0, 0);
                acc[1][1] = __builtin_amdgcn_mfma_f32_32x32x16_bf16(a1, b1, acc[1][1], 0, 0, 0);
                acc[1][2] = __builtin_amdgcn_mfma_f32_32x32x16_bf16(a1, b2, acc[1][2], 0, 0, 0);
                acc[1][3] = __builtin_amdgcn_mfma_f32_32x32x16_bf16(a1, b3, acc[1][3], 0, 0, 0);
            }
            __syncthreads();
        }

        // Epilogue for this m-chunk: 4 quarters of 32 rows.
#pragma unroll
        for (int q = 0; q < 4; ++q) {
            if ((wave & 1) == (q >> 1)) {
                const int msub = q & 1;
#pragma unroll
                for (int n = 0; n < 4; ++n) {
                    const int c = jhalf*128 + n*32 + l31;
#pragma unroll
                    for (int r = 0; r < 16; ++r) {
                        const int row = (r & 3) + 8*(r >> 2) + rbase;
                        TM[row*TMROW + c] = acc[msub][n][r];
                    }
                }
            }
            __syncthreads();
            {
                const int ml  = tid & 31;
                const int cs8 = tid >> 5;          // 0..7, 32 cols each
                const int mg  = m0 + q*32 + ml;
                const float* tmr = TM + ml*TMROW + cs8*32;
                const unsigned short* ipr = ip + mg*HH + cs8*32;
                float s = 0.0f;
#pragma unroll
                for (int c8 = 0; c8 < 4; ++c8) {
                    uint4 uip = *(const uint4*)(ipr + c8*8);
                    const unsigned short* pi = (const unsigned short*)&uip;
                    F8 fb = load8(bc, i*HH + cs8*32 + c8*8, isf32);
#pragma unroll
                    for (int j = 0; j < 8; ++j)
                        s = fmaf(tmr[c8*8 + j] + fb.v[j], bf2f(pi[j]), s);
                }
                part[ml*9 + cs8] = s;
            }
            __syncthreads();
            if (tid < 32) {
                float s = 0.0f;
#pragma unroll
                for (int w2 = 0; w2 < 8; ++w2) s += part[tid*9 + w2];
                const int mg = m0 + q*32 + tid;
                if (isf32) {
                    float* o = (float*)out;
                    o[mg*HH + i] = s;
                    if (mg >= MM - BB) o[MM*HH + (mg - (MM-BB))*HH + i] = s;
                } else {
                    unsigned short* o = (unsigned short*)out;
                    const unsigned short v = f2bf(s);
                    o[mg*HH + i] = v;
                    if (mg >= MM - BB) o[MM*HH + (mg - (MM-BB))*HH + i] = v;
                }
            }
            __syncthreads();
        }
    }
}

// ---------------------------------------------------------------------------
extern "C" void kernel_launch(void* const* d_in, const int* in_sizes, int n_in,
                              void* d_out, int out_size, void* d_ws, size_t ws_size,
                              hipStream_t stream) {
    const void* x     = d_in[0];
    const void* w_i2h = d_in[1];
    const void* b_i2h = d_in[2];
    // d_in[3]=w_h2h, d_in[4]=b_h2h: dead code (reference overwrites hidden=transformed)
    const void* w_i2c = d_in[5];
    const void* b_i2c = d_in[6];
    const void* w_c2c = d_in[7];
    const void* b_c2c = d_in[8];
    const void* w_c2t = d_in[9];
    const void* b_c2t = d_in[10];
    const int* ns     = (const int*)d_in[11];

    // ws layout: ip bf16 [2048,256] | ctx_hist bf16 | cin f32 | flag int
    unsigned short* ip  = (unsigned short*)d_ws;
    unsigned short* ch  = (unsigned short*)((char*)d_ws + (size_t)MM*HH*2);
    float* cin          = (float*)((char*)d_ws + (size_t)MM*HH*4);
    int* flag           = (int*)((char*)d_ws + (size_t)MM*HH*8);

    k0_sniff<<<1, 256, 0, stream>>>((const unsigned short*)x, flag);
    k1_proj<<<64, 256, 0, stream>>>(x, w_i2h, b_i2h, w_i2c, b_i2c, flag, ip, cin);
    k2_ctx<<<BB, 256, 0, stream>>>(w_c2c, b_c2c, cin, ns, flag, ch, d_out);
    k3_main<<<dim3(2, 256), 256, 0, stream>>>(ch, w_c2t, b_c2t, ip, flag, d_out);
}

// Round 4
// 341.533 us; speedup vs baseline: 1.7886x; 1.4671x over previous
//
#include <hip/hip_runtime.h>

// Problem constants (T=64, B=32, I=128, H=256, alpha=0.2)
#define TT 64
#define BB 32
#define II 128
#define HH 256
#define MM (TT*BB)   // 2048

typedef __bf16  bf16x8  __attribute__((ext_vector_type(8)));
typedef float   f32x16  __attribute__((ext_vector_type(16)));
typedef _Float16 half2v __attribute__((ext_vector_type(2)));

__device__ __forceinline__ float bf2f(unsigned short u) {
    union { unsigned int i; float f; } v; v.i = ((unsigned int)u) << 16; return v.f;
}
__device__ __forceinline__ unsigned short f2bf(float f) {
    union { float f; unsigned int i; } v; v.f = f;
    unsigned int r = v.i + 0x7fffu + ((v.i >> 16) & 1u);
    return (unsigned short)(r >> 16);
}

// Dual-dtype loaders: external tensors may be fp32 or bf16; runtime flag decides.
struct F8 { float v[8]; };
__device__ __forceinline__ F8 load8(const void* base, int idx, int isf32) {
    F8 r;
    if (isf32) {
        const float4* p = (const float4*)((const float*)base + idx);
        float4 a = p[0], b = p[1];
        r.v[0]=a.x; r.v[1]=a.y; r.v[2]=a.z; r.v[3]=a.w;
        r.v[4]=b.x; r.v[5]=b.y; r.v[6]=b.z; r.v[7]=b.w;
    } else {
        uint4 u = *(const uint4*)((const unsigned short*)base + idx);
        const unsigned short* p = (const unsigned short*)&u;
#pragma unroll
        for (int j = 0; j < 8; ++j) r.v[j] = bf2f(p[j]);
    }
    return r;
}
__device__ __forceinline__ float load1(const void* base, int idx, int isf32) {
    return isf32 ? ((const float*)base)[idx]
                 : bf2f(((const unsigned short*)base)[idx]);
}

__device__ __forceinline__ float fdot2f(half2v a, half2v b, float c) {
#if __has_builtin(__builtin_amdgcn_fdot2)
    return __builtin_amdgcn_fdot2(a, b, c, false);
#else
    return c + (float)a.x*(float)b.x + (float)a.y*(float)b.y;
#endif
}

// ---------------------------------------------------------------------------
// K0: dtype sniffer (fp32 read as ushorts -> ~25% have exponent >= 0xC0).
// ---------------------------------------------------------------------------
__global__ __launch_bounds__(256) void k0_sniff(
    const unsigned short* __restrict__ x, int* __restrict__ flag)
{
    __shared__ int cnt;
    if (threadIdx.x == 0) cnt = 0;
    __syncthreads();
    int c = 0;
    for (int i = threadIdx.x; i < 8192; i += 256) {
        unsigned int e = (x[i] >> 7) & 0xFFu;
        if (e >= 0xC0u) ++c;
    }
    atomicAdd(&cnt, c);
    __syncthreads();
    if (threadIdx.x == 0) flag[0] = (cnt > 16) ? 1 : 0;
}

// ---------------------------------------------------------------------------
// K1 v2 (unchanged from R3): weights resident in VGPRs, 32 m per block.
// ---------------------------------------------------------------------------
__global__ __launch_bounds__(256) void k1_proj(
    const void* __restrict__ x,
    const void* __restrict__ w_i2h,
    const void* __restrict__ b_i2h,
    const void* __restrict__ w_i2c,
    const void* __restrict__ b_i2c,
    const int* __restrict__ flagp,
    unsigned short* __restrict__ ip,
    float* __restrict__ cin)
{
    const int isf32 = *flagp;
    const int tid = threadIdx.x;
    const int h = tid;
    const int mbase = blockIdx.x * 32;
    __shared__ __align__(16) _Float16 xs[32][II];   // 8 KB

    half2v w1[II/2], w2[II/2];
#pragma unroll
    for (int c8 = 0; c8 < II/8; ++c8) {
        F8 f1 = load8(w_i2h, h*II + c8*8, isf32);
        F8 f2 = load8(w_i2c, h*II + c8*8, isf32);
#pragma unroll
        for (int j = 0; j < 4; ++j) {
            half2v a; a.x = (_Float16)f1.v[2*j]; a.y = (_Float16)f1.v[2*j+1];
            half2v b; b.x = (_Float16)f2.v[2*j]; b.y = (_Float16)f2.v[2*j+1];
            w1[c8*4 + j] = a;
            w2[c8*4 + j] = b;
        }
    }
    const float bb1 = load1(b_i2h, h, isf32);
    const float bb2 = load1(b_i2c, h, isf32);

    for (int u = tid; u < 32*II; u += 256)
        xs[u >> 7][u & (II-1)] = (_Float16)load1(x, (mbase + (u >> 7))*II + (u & (II-1)), isf32);
    __syncthreads();

    for (int mm = 0; mm < 32; ++mm) {
        const half2v* xv = (const half2v*)xs[mm];
        float a0=0,a1=0,a2=0,a3=0, c0=0,c1=0,c2=0,c3=0;
#pragma unroll
        for (int r = 0; r < II/2; r += 4) {
            half2v x0 = xv[r], x1 = xv[r+1], x2 = xv[r+2], x3 = xv[r+3];
            a0 = fdot2f(w1[r],   x0, a0);
            a1 = fdot2f(w1[r+1], x1, a1);
            a2 = fdot2f(w1[r+2], x2, a2);
            a3 = fdot2f(w1[r+3], x3, a3);
            c0 = fdot2f(w2[r],   x0, c0);
            c1 = fdot2f(w2[r+1], x1, c1);
            c2 = fdot2f(w2[r+2], x2, c2);
            c3 = fdot2f(w2[r+3], x3, c3);
        }
        ip[(mbase+mm)*HH + h]  = f2bf(((a0+a1)+(a2+a3)) + bb1);
        cin[(mbase+mm)*HH + h] = ((c0+c1)+(c2+c3)) + bb2;
    }
}

// ---------------------------------------------------------------------------
// K2 v2 (unchanged from R3): per-sample context chains, double-buffered LDS.
// ---------------------------------------------------------------------------
__global__ __launch_bounds__(256) void k2_ctx(
    const void* __restrict__ w_c2c,
    const void* __restrict__ b_c2c,
    const float* __restrict__ cin,
    const int* __restrict__ ns_ptr,
    const int* __restrict__ flagp,
    unsigned short* __restrict__ ctx_hist,
    void* __restrict__ out_base)
{
    const int isf32 = *flagp;
    const int b = blockIdx.x;
    const int h = threadIdx.x;
    const int ns = max(1, *ns_ptr);

    __shared__ __align__(16) _Float16 cs[2][HH];

    half2v w[HH/2];
#pragma unroll
    for (int c8 = 0; c8 < HH/8; ++c8) {
        F8 f = load8(w_c2c, h*HH + c8*8, isf32);
#pragma unroll
        for (int j = 0; j < 4; ++j) {
            half2v hv;
            hv.x = (_Float16)f.v[2*j];
            hv.y = (_Float16)f.v[2*j+1];
            w[c8*4 + j] = hv;
        }
    }
    const float bcc = load1(b_c2c, h, isf32);
    float ctxv = 0.0f;
    cs[0][h] = (_Float16)0.0f;
    __syncthreads();
    int cur = 0;

    for (int t = 0; t < TT; ++t) {
        const float cinv = cin[(t*BB + b)*HH + h];
        for (int s = 0; s < ns; ++s) {
            if (s == ns-1) ctx_hist[(t*BB + b)*HH + h] = f2bf(ctxv);
            float p0=0,p1=0,p2=0,p3=0;
            const float4* cp4 = (const float4*)cs[cur];   // 16B = 4 half2
#pragma unroll
            for (int r4 = 0; r4 < HH/8; ++r4) {
                float4 blob = cp4[r4];
                const half2v* c2 = (const half2v*)&blob;
                p0 = fdot2f(w[r4*4+0], c2[0], p0);
                p1 = fdot2f(w[r4*4+1], c2[1], p1);
                p2 = fdot2f(w[r4*4+2], c2[2], p2);
                p3 = fdot2f(w[r4*4+3], c2[3], p3);
            }
            float cnew = fmaxf(((p0+p1)+(p2+p3)) + bcc + cinv, 0.0f);
            ctxv = 0.8f*ctxv + 0.2f*cnew;
            cs[cur^1][h] = (_Float16)ctxv;
            cur ^= 1;
            __syncthreads();
        }
    }
    const int cofs = MM*HH + BB*HH + b*HH + h;
    if (isf32) ((float*)out_base)[cofs] = ctxv;
    else       ((unsigned short*)out_base)[cofs] = f2bf(ctxv);
}

// ---------------------------------------------------------------------------
// K3 v3: B-resident-in-LDS. Grid 256 (one block per i), 512 threads, 1/CU.
// LDS (160 KiB dynamic): Bs [256][256] bf16 XOR-swizzled (131072 B) +
// A region (32768 B) holding per-kc A chunks [256][64] swizzled, overlaid by
// a [32][256] f32 TM buffer (unit-swizzled) during the epilogue.
// B staged ONCE per block (compulsory 67 MB total); A/ip are L2-resident.
// Wave tile: 8 waves = 4 m-subblocks(64) x 2 j-halves(128); 32x32x16 MFMA.
// Swizzle: 16B unit column c stored at c ^ (row & 7)  -> no padding needed.
// ---------------------------------------------------------------------------
__global__ __launch_bounds__(512, 2) void k3_main(
    const unsigned short* __restrict__ ctx_hist,  // [2048,256] bf16 (internal)
    const void* __restrict__ wc,                  // [65536,256] external
    const void* __restrict__ bc,                  // [65536]     external
    const unsigned short* __restrict__ ip,        // [2048,256] bf16 (internal)
    const int* __restrict__ flagp,
    void* __restrict__ out)
{
    extern __shared__ __align__(16) unsigned char lds[];
    unsigned short* Bs = (unsigned short*)lds;              // 131072 B
    unsigned short* As = (unsigned short*)(lds + 131072);   // 32768 B
    float*          TMf = (float*)(lds + 131072);           // overlay

    const int isf32 = *flagp;
    const int tid  = threadIdx.x;
    const int lane = tid & 63;
    const int wave = tid >> 6;        // 0..7
    const int i    = blockIdx.x;      // 0..255
    const int mh   = wave & 3;        // m-subblock (64 rows)
    const int jh   = wave >> 2;       // j-half (128 cols)
    const int l31  = lane & 31;
    const int lhi  = lane >> 5;

    // epilogue roles
    const int eml = tid >> 4;         // 0..31 (row in 32-row chunk)
    const int ecs = tid & 15;         // 0..15 (16-col segment)

    // preload bc for this thread's epilogue cols
    float bcp[16];
    {
        F8 f0 = load8(bc, i*HH + ecs*16,     isf32);
        F8 f1 = load8(bc, i*HH + ecs*16 + 8, isf32);
#pragma unroll
        for (int j = 0; j < 8; ++j) { bcp[j] = f0.v[j]; bcp[8+j] = f1.v[j]; }
    }

    // ---- stage B once: 256 rows x 256 k, fp32/bf16 -> bf16, swizzled ----
#pragma unroll
    for (int p = 0; p < 16; ++p) {
        int u = tid + p*512;
        int row = u >> 5, cu = u & 31;
        F8 f = load8(wc, (i*HH + row)*HH + cu*8, isf32);
        unsigned short tmp[8];
#pragma unroll
        for (int j = 0; j < 8; ++j) tmp[j] = f2bf(f.v[j]);
        *(uint4*)(Bs + row*256 + ((cu ^ (row & 7)) << 3)) = *(const uint4*)tmp;
    }
    // first kc's barrier covers B visibility

    for (int mc = 0; mc < 8; ++mc) {
        const int m0 = mc * 256;

        f32x16 acc[2][4];
#pragma unroll
        for (int a = 0; a < 2; ++a)
#pragma unroll
            for (int n = 0; n < 4; ++n)
#pragma unroll
                for (int r = 0; r < 16; ++r) acc[a][n][r] = 0.0f;

#pragma unroll
        for (int kc = 0; kc < 4; ++kc) {
            const int k0 = kc * 64;
            // stage A chunk: 256 rows x 64 k, swizzled
#pragma unroll
            for (int p = 0; p < 4; ++p) {
                int u = tid + p*512;
                int row = u >> 3, cu = u & 7;
                uint4 v = *(const uint4*)(ctx_hist + (m0 + row)*HH + k0 + cu*8);
                *(uint4*)(As + row*64 + ((cu ^ (row & 7)) << 3)) = v;
            }
            __syncthreads();
#pragma unroll
            for (int ks = 0; ks < 4; ++ks) {
                const int cA = ks*2 + lhi;          // 0..7
                const int ra0 = mh*64 + l31;
                const int ra1 = ra0 + 32;
                bf16x8 a0 = *(const bf16x8*)(As + ra0*64 + ((cA ^ (ra0 & 7)) << 3));
                bf16x8 a1 = *(const bf16x8*)(As + ra1*64 + ((cA ^ (ra1 & 7)) << 3));
                const int cB = kc*8 + ks*2 + lhi;   // 0..31
                const int rb0 = jh*128 +       l31;
                const int rb1 = jh*128 + 32  + l31;
                const int rb2 = jh*128 + 64  + l31;
                const int rb3 = jh*128 + 96  + l31;
                bf16x8 b0 = *(const bf16x8*)(Bs + rb0*256 + ((cB ^ (rb0 & 7)) << 3));
                bf16x8 b1 = *(const bf16x8*)(Bs + rb1*256 + ((cB ^ (rb1 & 7)) << 3));
                bf16x8 b2 = *(const bf16x8*)(Bs + rb2*256 + ((cB ^ (rb2 & 7)) << 3));
                bf16x8 b3 = *(const bf16x8*)(Bs + rb3*256 + ((cB ^ (rb3 & 7)) << 3));
                acc[0][0] = __builtin_amdgcn_mfma_f32_32x32x16_bf16(a0, b0, acc[0][0], 0, 0, 0);
                acc[0][1] = __builtin_amdgcn_mfma_f32_32x32x16_bf16(a0, b1, acc[0][1], 0, 0, 0);
                acc[0][2] = __builtin_amdgcn_mfma_f32_32x32x16_bf16(a0, b2, acc[0][2], 0, 0, 0);
                acc[0][3] = __builtin_amdgcn_mfma_f32_32x32x16_bf16(a0, b3, acc[0][3], 0, 0, 0);
                acc[1][0] = __builtin_amdgcn_mfma_f32_32x32x16_bf16(a1, b0, acc[1][0], 0, 0, 0);
                acc[1][1] = __builtin_amdgcn_mfma_f32_32x32x16_bf16(a1, b1, acc[1][1], 0, 0, 0);
                acc[1][2] = __builtin_amdgcn_mfma_f32_32x32x16_bf16(a1, b2, acc[1][2], 0, 0, 0);
                acc[1][3] = __builtin_amdgcn_mfma_f32_32x32x16_bf16(a1, b3, acc[1][3], 0, 0, 0);
            }
            __syncthreads();
        }

        // ---- epilogue: 8 chunks of 32 rows; TM overlaid on A region ----
#pragma unroll
        for (int ch = 0; ch < 8; ++ch) {
            if (mh == (ch >> 1)) {
                const int a = ch & 1;
#pragma unroll
                for (int n = 0; n < 4; ++n) {
                    const int j  = jh*128 + n*32 + l31;
                    const int ju = j >> 2, jo = j & 3;
#pragma unroll
                    for (int r = 0; r < 16; ++r) {
                        const int row16 = (r & 3) + 8*(r >> 2) + 4*lhi;
                        TMf[row16*256 + ((ju ^ (row16 & 7)) << 2) + jo] = acc[a][n][r];
                    }
                }
            }
            __syncthreads();
            {
                const int g = m0 + ch*32 + eml;
                float ipf[16];
                {
                    uint4 u0 = *(const uint4*)(ip + g*HH + ecs*16);
                    uint4 u1 = *(const uint4*)(ip + g*HH + ecs*16 + 8);
                    const unsigned short* p0 = (const unsigned short*)&u0;
                    const unsigned short* p1 = (const unsigned short*)&u1;
#pragma unroll
                    for (int j = 0; j < 8; ++j) { ipf[j] = bf2f(p0[j]); ipf[8+j] = bf2f(p1[j]); }
                }
                const float4* TM4 = (const float4*)TMf;
                float s = 0.0f;
#pragma unroll
                for (int u = 0; u < 4; ++u) {
                    float4 t = TM4[eml*64 + ((ecs*4 + u) ^ (eml & 7))];
                    s = fmaf(t.x + bcp[u*4+0], ipf[u*4+0], s);
                    s = fmaf(t.y + bcp[u*4+1], ipf[u*4+1], s);
                    s = fmaf(t.z + bcp[u*4+2], ipf[u*4+2], s);
                    s = fmaf(t.w + bcp[u*4+3], ipf[u*4+3], s);
                }
                s += __shfl_xor(s, 1);
                s += __shfl_xor(s, 2);
                s += __shfl_xor(s, 4);
                s += __shfl_xor(s, 8);
                if (ecs == 0) {
                    if (isf32) {
                        float* o = (float*)out;
                        o[g*HH + i] = s;
                        if (g >= MM - BB) o[MM*HH + (g - (MM-BB))*HH + i] = s;
                    } else {
                        unsigned short* o = (unsigned short*)out;
                        const unsigned short v = f2bf(s);
                        o[g*HH + i] = v;
                        if (g >= MM - BB) o[MM*HH + (g - (MM-BB))*HH + i] = v;
                    }
                }
            }
            __syncthreads();
        }
    }
}

// ---------------------------------------------------------------------------
extern "C" void kernel_launch(void* const* d_in, const int* in_sizes, int n_in,
                              void* d_out, int out_size, void* d_ws, size_t ws_size,
                              hipStream_t stream) {
    const void* x     = d_in[0];
    const void* w_i2h = d_in[1];
    const void* b_i2h = d_in[2];
    // d_in[3]=w_h2h, d_in[4]=b_h2h: dead code (reference overwrites hidden=transformed)
    const void* w_i2c = d_in[5];
    const void* b_i2c = d_in[6];
    const void* w_c2c = d_in[7];
    const void* b_c2c = d_in[8];
    const void* w_c2t = d_in[9];
    const void* b_c2t = d_in[10];
    const int* ns     = (const int*)d_in[11];

    // ws layout: ip bf16 [2048,256] | ctx_hist bf16 | cin f32 | flag int
    unsigned short* ip  = (unsigned short*)d_ws;
    unsigned short* ch  = (unsigned short*)((char*)d_ws + (size_t)MM*HH*2);
    float* cin          = (float*)((char*)d_ws + (size_t)MM*HH*4);
    int* flag           = (int*)((char*)d_ws + (size_t)MM*HH*8);

    // allow 160 KiB dynamic LDS for k3 (host-side attribute; capture-safe)
    static bool attr_done = false;
    (void)hipFuncSetAttribute((const void*)k3_main,
                              hipFuncAttributeMaxDynamicSharedMemorySize, 163840);
    (void)attr_done;

    k0_sniff<<<1, 256, 0, stream>>>((const unsigned short*)x, flag);
    k1_proj<<<64, 256, 0, stream>>>(x, w_i2h, b_i2h, w_i2c, b_i2c, flag, ip, cin);
    k2_ctx<<<BB, 256, 0, stream>>>(w_c2c, b_c2c, cin, ns, flag, ch, d_out);
    k3_main<<<256, 512, 163840, stream>>>(ch, w_c2t, b_c2t, ip, flag, d_out);
}